// Round 2
// baseline (595.738 us; speedup 1.0000x reference)
//
#include <hip/hip_runtime.h>
#include <hip/hip_bf16.h>

typedef __attribute__((ext_vector_type(8))) short bf16x8;
typedef __attribute__((ext_vector_type(4))) float f32x4;

#define HWSZ 4096
#define NPIX 16384

__device__ inline float bf2f(__hip_bfloat16 v) { return __bfloat162float(v); }

// ---------------- weight fp32 -> bf16 conversion ----------------
// wbf layout per bi (elems): qw 0, kw 65536, vw 131072, pw 196608, fc1w 262144, fc2w 524288; total 786432
__global__ __launch_bounds__(256) void convert_k(
    const float* __restrict__ qw, const float* __restrict__ kw,
    const float* __restrict__ vw, const float* __restrict__ pw,
    const float* __restrict__ f1, const float* __restrict__ f2,
    __hip_bfloat16* __restrict__ out)
{
  int idx = blockIdx.x * 256 + threadIdx.x;
  if (idx >= 2 * 786432) return;
  int bi = idx / 786432;
  int r  = idx - bi * 786432;
  float v;
  if      (r <  65536) v = qw[bi*65536 + r];
  else if (r < 131072) v = kw[bi*65536 + r - 65536];
  else if (r < 196608) v = vw[bi*65536 + r - 131072];
  else if (r < 262144) v = pw[bi*65536 + r - 196608];
  else if (r < 524288) v = f1[bi*262144 + r - 262144];
  else                 v = f2[bi*262144 + r - 524288];
  out[idx] = __float2bfloat16(v);
}

// ---------------- prep: LN1 over channels of (av*vi + ai*ir), BCHW -> (pix, ch) ----------------
__global__ __launch_bounds__(256) void prep_k(
    const float* __restrict__ x,     // (2,4,256,64,64)
    const float* __restrict__ nw, const float* __restrict__ nb,  // [256]
    __hip_bfloat16* __restrict__ ln_out,   // [16384][256]
    float* __restrict__ diff_out,          // nullable, [16384][256]
    float av, float ai)
{
  __shared__ float tile[32][257];
  __shared__ float ps[8][32], pss[8][32], muA[32], rsA[32];
  int t = threadIdx.x;
  int pix0 = blockIdx.x * 32;
  int b = pix0 >> 12, hw0 = pix0 & 4095;
  const float* vi = x + (size_t)b * 256 * HWSZ;
  const float* ir = x + (size_t)(4 + b) * 256 * HWSZ;

  for (int it = 0; it < 32; ++it) {
    int idx = it * 256 + t;
    int p = idx & 31, c = idx >> 5;
    size_t off = (size_t)c * HWSZ + hw0 + p;
    tile[p][c] = av * vi[off] + ai * ir[off];
  }
  __syncthreads();
  {
    int p = t & 31, q = t >> 5;
    float s = 0.f, ss = 0.f;
    for (int i = 0; i < 32; ++i) { float v = tile[p][q*32 + i]; s += v; ss += v*v; }
    ps[q][p] = s; pss[q][p] = ss;
  }
  __syncthreads();
  if (t < 32) {
    float s = 0.f, ss = 0.f;
    for (int q = 0; q < 8; ++q) { s += ps[q][t]; ss += pss[q][t]; }
    float mu = s * (1.f/256.f);
    float var = ss * (1.f/256.f) - mu*mu;
    muA[t] = mu; rsA[t] = rsqrtf(var + 1e-5f);
  }
  __syncthreads();
  for (int it = 0; it < 32; ++it) {
    int pp = it, c = t;
    float v = tile[pp][c];
    float o = (v - muA[pp]) * rsA[pp] * nw[c] + nb[c];
    ln_out[(size_t)(pix0 + pp) * 256 + c] = __float2bfloat16(o);
    if (diff_out) diff_out[(size_t)(pix0 + pp) * 256 + c] = v;
  }
}

// ---------------- MFMA GEMM: C[M x N] = A[M x K] * W[N x K]^T ----------------
// block 256 thr = 4 waves (2x2), wave computes 32x32 via 2x2 frags of 16x16x32 bf16.
// EPI 0: bf16 out at [row*ldc + col]
// EPI 1: fp32 out = acc + bias[col] + res[row*Nres + col]
// EPI 2: bf16 out = gelu(acc + bias[col])
// EPI 3: fp32 BCHW direct: out[(b*256+col)*4096 + hw] = acc + bias[col] + res[row*Nres+col]
template<int EPI>
__global__ __launch_bounds__(256) void gemm_k(
    const short* __restrict__ A, const short* __restrict__ W,
    void* __restrict__ outp, const float* __restrict__ bias,
    const float* __restrict__ res,
    int K, int ldc, int Nres, int row_base)
{
  int tid = threadIdx.x;
  int l = tid & 63, wv = tid >> 6;
  int m0 = blockIdx.x * 64 + (wv >> 1) * 32;
  int n0 = blockIdx.y * 64 + (wv & 1) * 32;
  int lr = l & 15;
  int lk = (l >> 4) * 8;
  f32x4 acc00 = {0,0,0,0}, acc01 = {0,0,0,0}, acc10 = {0,0,0,0}, acc11 = {0,0,0,0};
  const short* pa = A + (size_t)(m0 + lr) * K + lk;
  const short* pb = W + (size_t)(n0 + lr) * K + lk;
  size_t rstep = (size_t)16 * K;
  for (int k0 = 0; k0 < K; k0 += 32) {
    bf16x8 a0 = *(const bf16x8*)(pa + k0);
    bf16x8 a1 = *(const bf16x8*)(pa + rstep + k0);
    bf16x8 b0 = *(const bf16x8*)(pb + k0);
    bf16x8 b1 = *(const bf16x8*)(pb + rstep + k0);
    acc00 = __builtin_amdgcn_mfma_f32_16x16x32_bf16(a0, b0, acc00, 0, 0, 0);
    acc01 = __builtin_amdgcn_mfma_f32_16x16x32_bf16(a0, b1, acc01, 0, 0, 0);
    acc10 = __builtin_amdgcn_mfma_f32_16x16x32_bf16(a1, b0, acc10, 0, 0, 0);
    acc11 = __builtin_amdgcn_mfma_f32_16x16x32_bf16(a1, b1, acc11, 0, 0, 0);
  }
  int rq = (l >> 4) * 4;
  #pragma unroll
  for (int mi = 0; mi < 2; ++mi)
  #pragma unroll
  for (int ni = 0; ni < 2; ++ni) {
    f32x4 a = (mi == 0) ? (ni == 0 ? acc00 : acc01) : (ni == 0 ? acc10 : acc11);
    #pragma unroll
    for (int r = 0; r < 4; ++r) {
      int row = m0 + mi*16 + rq + r;
      int col = n0 + ni*16 + lr;
      float v = a[r];
      if (EPI == 0) {
        ((__hip_bfloat16*)outp)[(size_t)row * ldc + col] = __float2bfloat16(v);
      } else if (EPI == 1) {
        v += bias[col] + res[(size_t)row * Nres + col];
        ((float*)outp)[(size_t)row * ldc + col] = v;
      } else if (EPI == 2) {
        v += bias[col];
        v = 0.5f * v * (1.f + erff(v * 0.70710678118654752f));
        ((__hip_bfloat16*)outp)[(size_t)row * ldc + col] = __float2bfloat16(v);
      } else {
        v += bias[col] + res[(size_t)row * Nres + col];
        int gpix = row + row_base;
        int b = gpix >> 12, hw = gpix & 4095;
        ((float*)outp)[(size_t)(b * 256 + col) * HWSZ + hw] = v;
      }
    }
  }
}

// ---------------- dilated local attention ----------------
// q/k/v: [16384][256] bf16 each. One wave per (pixel, group).
__global__ __launch_bounds__(256) void attn_k(
    const __hip_bfloat16* __restrict__ Q,
    const __hip_bfloat16* __restrict__ Kb,
    const __hip_bfloat16* __restrict__ Vb,
    __hip_bfloat16* __restrict__ out)   // [16384][256] bf16
{
  int unit = blockIdx.x * 4 + (threadIdx.x >> 6);
  int l = threadIdx.x & 63;
  int g = unit & 3;
  int pix = unit >> 2;
  int dil = g + 1;
  int y = (pix >> 6) & 63, xc = pix & 63;
  int col = g * 64 + l;
  float q = bf2f(Q[(size_t)pix * 256 + col]);
  float logit[9];
  #pragma unroll
  for (int t = 0; t < 9; ++t) {
    int ny = y + (t / 3 - 1) * dil;
    int nx = xc + (t % 3 - 1) * dil;
    float p = 0.f;
    if ((unsigned)ny < 64u && (unsigned)nx < 64u) {
      int np = (pix & ~4095) | (ny * 64 + nx);
      p = q * bf2f(Kb[(size_t)np * 256 + col]);
    }
    #pragma unroll
    for (int off = 16; off; off >>= 1) p += __shfl_xor(p, off);  // 32-lane = head reduce
    logit[t] = p * 0.17677669529663687f;   // 32^-0.5
  }
  float m = logit[0];
  #pragma unroll
  for (int t = 1; t < 9; ++t) m = fmaxf(m, logit[t]);
  float den = 0.f, wgt[9];
  #pragma unroll
  for (int t = 0; t < 9; ++t) { wgt[t] = expf(logit[t] - m); den += wgt[t]; }
  float inv = 1.f / den;
  float acc = 0.f;
  #pragma unroll
  for (int t = 0; t < 9; ++t) {
    int ny = y + (t / 3 - 1) * dil;
    int nx = xc + (t % 3 - 1) * dil;
    if ((unsigned)ny < 64u && (unsigned)nx < 64u) {
      int np = (pix & ~4095) | (ny * 64 + nx);
      acc += wgt[t] * inv * bf2f(Vb[(size_t)np * 256 + col]);
    }
  }
  out[(size_t)pix * 256 + col] = __float2bfloat16(acc);
}

// ---------------- LN2: fp32 (pix,ch) -> bf16 (pix,ch) ----------------
__global__ __launch_bounds__(256) void ln2_k(
    const float* __restrict__ xm, const float* __restrict__ w2,
    const float* __restrict__ b2, __hip_bfloat16* __restrict__ h)
{
  int pix = blockIdx.x * 4 + (threadIdx.x >> 6);
  int l = threadIdx.x & 63;
  const float4 v = *(const float4*)(xm + (size_t)pix * 256 + l * 4);
  float s  = v.x + v.y + v.z + v.w;
  float ss = v.x*v.x + v.y*v.y + v.z*v.z + v.w*v.w;
  #pragma unroll
  for (int off = 32; off; off >>= 1) { s += __shfl_xor(s, off); ss += __shfl_xor(ss, off); }
  float mu = s * (1.f/256.f);
  float rstd = rsqrtf(ss * (1.f/256.f) - mu*mu + 1e-5f);
  float vv[4] = {v.x, v.y, v.z, v.w};
  #pragma unroll
  for (int j = 0; j < 4; ++j) {
    int c = l * 4 + j;
    h[(size_t)pix * 256 + c] = __float2bfloat16((vv[j] - mu) * rstd * w2[c] + b2[c]);
  }
}

extern "C" void kernel_launch(void* const* d_in, const int* in_sizes, int n_in,
                              void* d_out, int out_size, void* d_ws, size_t ws_size,
                              hipStream_t stream)
{
  const float* x   = (const float*)d_in[0];
  const float* n1w = (const float*)d_in[1];
  const float* n1b = (const float*)d_in[2];
  const float* qw  = (const float*)d_in[3];
  const float* kw  = (const float*)d_in[4];
  const float* vw  = (const float*)d_in[5];
  const float* pw  = (const float*)d_in[6];
  const float* pb  = (const float*)d_in[7];
  const float* n2w = (const float*)d_in[8];
  const float* n2b = (const float*)d_in[9];
  const float* f1w = (const float*)d_in[10];
  const float* f1b = (const float*)d_in[11];
  const float* f2w = (const float*)d_in[12];
  const float* f2b = (const float*)d_in[13];
  float* outp = (float*)d_out;
  char* ws = (char*)d_ws;

  const size_t MB = 1024 * 1024;
  // Workspace high-water: 51 MB. Buffer lifetimes (per bi iteration):
  //   [0,3)   wbf  : bf16 weights (whole session)
  //   [3,11)  B    : ln1a -> kbuf -> hb(ln2 out)
  //   [11,19) C    : ln1b -> attnb -> h1h (low half)
  //   [19,35) D    : diff fp32 -> h1h (high half)
  //   [35,43) E    : qbuf -> xmid2 (low half)
  //   [43,51) F    : vbuf -> xmid2 (high half)
  __hip_bfloat16* wbf   = (__hip_bfloat16*)(ws);
  __hip_bfloat16* ln1a  = (__hip_bfloat16*)(ws + 3*MB);
  __hip_bfloat16* ln1b  = (__hip_bfloat16*)(ws + 11*MB);
  float*          diff  = (float*)(ws + 19*MB);
  __hip_bfloat16* qbuf  = (__hip_bfloat16*)(ws + 35*MB);
  __hip_bfloat16* kbuf  = (__hip_bfloat16*)(ws + 3*MB);    // alias B (ln1a dead after Q gemm)
  __hip_bfloat16* vbuf  = (__hip_bfloat16*)(ws + 43*MB);
  __hip_bfloat16* attnb = (__hip_bfloat16*)(ws + 11*MB);   // alias C (ln1b dead after K/V gemms)
  float*          xmid2 = (float*)(ws + 35*MB);            // alias E+F (q/v dead after attn)
  __hip_bfloat16* hb    = (__hip_bfloat16*)(ws + 3*MB);    // alias B (kbuf dead after attn)
  __hip_bfloat16* h1h   = (__hip_bfloat16*)(ws + 11*MB);   // alias C+D (attnb/diff dead after proj)

  convert_k<<<6144, 256, 0, stream>>>(qw, kw, vw, pw, f1w, f2w, wbf);

  for (int bi = 0; bi < 2; ++bi) {
    const short* wq = (const short*)(wbf + (size_t)bi * 786432);
    const short* wk = wq + 65536;
    const short* wv = wq + 131072;
    const short* wp = wq + 196608;
    const short* w1 = wq + 262144;
    const short* w2 = wq + 524288;
    // x1 = av*vi + ai*ir ; x2(=x3) = bv*vi + bb*ir
    float av = (bi == 0) ? 1.f : -1.f, ai = (bi == 0) ? -1.f : 1.f;
    float bv = (bi == 0) ? 0.f : 1.f,  bb = (bi == 0) ? 1.f : 0.f;

    prep_k<<<512, 256, 0, stream>>>(x, n1w + bi*256, n1b + bi*256, ln1a, diff, av, ai);
    prep_k<<<512, 256, 0, stream>>>(x, n1w + bi*256, n1b + bi*256, ln1b, nullptr, bv, bb);

    dim3 g4(256, 4);
    gemm_k<0><<<g4, 256, 0, stream>>>((const short*)ln1a, wq, qbuf, nullptr, nullptr, 256, 256, 0, 0);
    gemm_k<0><<<g4, 256, 0, stream>>>((const short*)ln1b, wk, kbuf, nullptr, nullptr, 256, 256, 0, 0);
    gemm_k<0><<<g4, 256, 0, stream>>>((const short*)ln1b, wv, vbuf, nullptr, nullptr, 256, 256, 0, 0);

    attn_k<<<16384, 256, 0, stream>>>(qbuf, kbuf, vbuf, attnb);

    gemm_k<1><<<g4, 256, 0, stream>>>((const short*)attnb, wp, xmid2, pb + bi*256, diff, 256, 256, 256, 0);
    ln2_k<<<4096, 256, 0, stream>>>(xmid2, n2w + bi*256, n2b + bi*256, hb);

    // row-split FFN: two passes of 8192 rows so h1 needs only 16 MB
    float* outb = outp + (size_t)bi * 4194304;
    for (int pass = 0; pass < 2; ++pass) {
      const short* hbp = (const short*)hb + (size_t)pass * 8192 * 256;
      const float* xmp = xmid2 + (size_t)pass * 8192 * 256;
      dim3 gf1(128, 16), gf2(128, 4);
      gemm_k<2><<<gf1, 256, 0, stream>>>(hbp, w1, h1h, f1b + bi*1024, nullptr, 256, 1024, 0, 0);
      gemm_k<3><<<gf2, 256, 0, stream>>>((const short*)h1h, w2, outb, f2b + bi*256, xmp, 1024, 256, 256, pass * 8192);
    }
  }
}

// Round 3
// 297.126 us; speedup vs baseline: 2.0050x; 2.0050x over previous
//
#include <hip/hip_runtime.h>
#include <hip/hip_bf16.h>

typedef __attribute__((ext_vector_type(8))) short bf16x8;
typedef __attribute__((ext_vector_type(4))) float f32x4;

#define HWSZ 4096
#define NPIX 16384

__device__ inline float b2f(short s) {
  return __uint_as_float(((unsigned)(unsigned short)s) << 16);
}
__device__ inline short f2b(float f) {
  __hip_bfloat16 h = __float2bfloat16(f);
  return *(short*)&h;
}
__device__ inline void gl16(const short* g, short* l) {
  __builtin_amdgcn_global_load_lds(
      (const __attribute__((address_space(1))) unsigned int*)g,
      (__attribute__((address_space(3))) unsigned int*)l, 16, 0, 0);
}

// ---------------- weight fp32 -> bf16 conversion ----------------
// wbf per bi (elems): qw 0, kw 65536, vw 131072, pw 196608, fc1w 262144, fc2w 524288; total 786432
__global__ __launch_bounds__(256) void convert_k(
    const float* __restrict__ qw, const float* __restrict__ kw,
    const float* __restrict__ vw, const float* __restrict__ pw,
    const float* __restrict__ f1, const float* __restrict__ f2,
    __hip_bfloat16* __restrict__ out)
{
  int idx = blockIdx.x * 256 + threadIdx.x;
  if (idx >= 2 * 786432) return;
  int bi = idx / 786432;
  int r  = idx - bi * 786432;
  float v;
  if      (r <  65536) v = qw[bi*65536 + r];
  else if (r < 131072) v = kw[bi*65536 + r - 65536];
  else if (r < 196608) v = vw[bi*65536 + r - 131072];
  else if (r < 262144) v = pw[bi*65536 + r - 196608];
  else if (r < 524288) v = f1[bi*262144 + r - 262144];
  else                 v = f2[bi*262144 + r - 524288];
  out[idx] = __float2bfloat16(v);
}

// ---------------- fused prep: both LN1 variants + raw diff, BCHW -> (pix, ch) ----------------
__global__ __launch_bounds__(256) void prep2_k(
    const float* __restrict__ x,     // (2,4,256,64,64)
    const float* __restrict__ nw, const float* __restrict__ nb,
    __hip_bfloat16* __restrict__ ln1a,   // LN(av*vi+ai*ir)
    __hip_bfloat16* __restrict__ ln1b,   // LN(bv*vi+bb*ir)
    float* __restrict__ diff,            // av*vi+ai*ir (raw)
    float av, float ai, float bv, float bb)
{
  __shared__ float t1[16][257], t2[16][257];
  __shared__ float red[4][16][16];
  __shared__ float mu1[16], rs1[16], mu2[16], rs2[16];
  int t = threadIdx.x;
  int pix0 = blockIdx.x * 16;
  int b = pix0 >> 12, hw0 = pix0 & 4095;
  const float* vi = x + (size_t)b * 256 * HWSZ;
  const float* ir = x + (size_t)(4 + b) * 256 * HWSZ;

  for (int it = 0; it < 16; ++it) {
    int idx = it * 256 + t;
    int p = idx & 15, c = idx >> 4;
    size_t off = (size_t)c * HWSZ + hw0 + p;
    float a = vi[off], bb2 = ir[off];
    t1[p][c] = av * a + ai * bb2;
    t2[p][c] = bv * a + bb * bb2;
  }
  __syncthreads();
  {
    int p = t & 15, q = t >> 4;
    float s1 = 0, ss1 = 0, s2 = 0, ss2 = 0;
    for (int i = 0; i < 16; ++i) {
      float v = t1[p][q*16 + i]; s1 += v; ss1 += v*v;
      float u = t2[p][q*16 + i]; s2 += u; ss2 += u*u;
    }
    red[0][p][q] = s1; red[1][p][q] = ss1; red[2][p][q] = s2; red[3][p][q] = ss2;
  }
  __syncthreads();
  if (t < 32) {
    int p = t & 15, which = t >> 4;
    float s = 0, ss = 0;
    for (int q = 0; q < 16; ++q) { s += red[which*2][p][q]; ss += red[which*2+1][p][q]; }
    float mu = s * (1.f/256.f);
    float var = ss * (1.f/256.f) - mu*mu;
    float rs = rsqrtf(var + 1e-5f);
    if (which == 0) { mu1[p] = mu; rs1[p] = rs; }
    else            { mu2[p] = mu; rs2[p] = rs; }
  }
  __syncthreads();
  for (int it = 0; it < 16; ++it) {
    float v1 = t1[it][t], v2 = t2[it][t];
    size_t o = (size_t)(pix0 + it) * 256 + t;
    ln1a[o] = __float2bfloat16((v1 - mu1[it]) * rs1[it] * nw[t] + nb[t]);
    ln1b[o] = __float2bfloat16((v2 - mu2[it]) * rs2[it] * nw[t] + nb[t]);
    diff[o] = v1;
  }
}

// ---------------- LDS-staged MFMA GEMM: C[M x N] = A[M x K] * W[N x K]^T ----------------
// Block tile 128 x BN, BK=32, 4 waves. BN=128: waves 2x2 (wave 64x64); BN=64: waves 4x1 (wave 32x64).
// LDS linear dest via global_load_lds; chunk swizzle c' = c ^ ((row>>1)&3) applied on SOURCE and READ.
// EPI 0: bf16 out[row*ldc+col]
// EPI 1: fp32 out = acc + bias[col] + res[row*Nres+col]
// EPI 2: bf16 out = gelu(acc + bias[col])
// EPI 3: fp32 BCHW: out[(b*256+col)*4096 + hw] = acc + bias[col] + res[row*Nres+col], gpix=row+row_base
template<int EPI, int BN>
__global__ __launch_bounds__(256) void gemm2_k(
    const short* __restrict__ A, const short* __restrict__ W,
    void* __restrict__ outp, const float* __restrict__ bias,
    const float* __restrict__ res,
    int K, int ldc, int Nres, int row_base)
{
  constexpr int NWN = (BN == 128) ? 2 : 1;
  constexpr int MI  = (BN == 128) ? 4 : 2;
  __shared__ __align__(16) short As[128 * 32];
  __shared__ __align__(16) short Bs[BN * 32];
  int tid = threadIdx.x;
  int l = tid & 63, wv = tid >> 6;
  int wm = (NWN == 2) ? (wv >> 1) : wv;
  int wn = (NWN == 2) ? (wv & 1) : 0;
  int m0 = blockIdx.x * 128;
  int n0 = blockIdx.y * BN;
  int lr = l & 15, lq = l >> 4;
  int qe = lq ^ ((lr >> 1) & 3);

  // staging: thread t -> LDS bytes [t*16, t*16+16) (+4096 for round 1); linear in lane order
  int srow = tid >> 2;
  int sw = (tid & 3) ^ ((srow >> 1) & 3);
  const short* gA0 = A + (size_t)(m0 + srow) * K + sw * 8;
  const short* gA1 = A + (size_t)(m0 + srow + 64) * K + sw * 8;
  const short* gB0 = W + (size_t)(n0 + srow) * K + sw * 8;
  const short* gB1 = (BN == 128) ? (W + (size_t)(n0 + srow + 64) * K + sw * 8) : nullptr;
  short* lA0 = As + tid * 8;
  short* lA1 = As + 2048 + tid * 8;
  short* lB0 = Bs + tid * 8;
  short* lB1 = (BN == 128) ? (Bs + 2048 + tid * 8) : nullptr;

  f32x4 acc[MI][4];
  #pragma unroll
  for (int mi = 0; mi < MI; ++mi)
    #pragma unroll
    for (int ni = 0; ni < 4; ++ni) acc[mi][ni] = (f32x4){0.f, 0.f, 0.f, 0.f};

  const bf16x8* Ab = (const bf16x8*)As;
  const bf16x8* Bb = (const bf16x8*)Bs;
  int aoff = (wm * MI * 16 + lr) * 4 + qe;
  int boff = (wn * 64 + lr) * 4 + qe;

  for (int k0 = 0; k0 < K; k0 += 32) {
    gl16(gA0 + k0, lA0);
    gl16(gA1 + k0, lA1);
    gl16(gB0 + k0, lB0);
    if constexpr (BN == 128) gl16(gB1 + k0, lB1);
    __syncthreads();
    bf16x8 af[MI], bfr[4];
    #pragma unroll
    for (int mi = 0; mi < MI; ++mi) af[mi] = Ab[aoff + mi * 64];
    #pragma unroll
    for (int ni = 0; ni < 4; ++ni) bfr[ni] = Bb[boff + ni * 64];
    #pragma unroll
    for (int mi = 0; mi < MI; ++mi)
      #pragma unroll
      for (int ni = 0; ni < 4; ++ni)
        acc[mi][ni] = __builtin_amdgcn_mfma_f32_16x16x32_bf16(af[mi], bfr[ni], acc[mi][ni], 0, 0, 0);
    __syncthreads();
  }

  #pragma unroll
  for (int mi = 0; mi < MI; ++mi)
  #pragma unroll
  for (int ni = 0; ni < 4; ++ni) {
    #pragma unroll
    for (int r = 0; r < 4; ++r) {
      int row = m0 + wm * MI * 16 + mi * 16 + lq * 4 + r;
      int col = n0 + wn * 64 + ni * 16 + lr;
      float v = acc[mi][ni][r];
      if (EPI == 0) {
        ((__hip_bfloat16*)outp)[(size_t)row * ldc + col] = __float2bfloat16(v);
      } else if (EPI == 1) {
        v += bias[col] + res[(size_t)row * Nres + col];
        ((float*)outp)[(size_t)row * ldc + col] = v;
      } else if (EPI == 2) {
        v += bias[col];
        v = 0.5f * v * (1.f + erff(v * 0.70710678118654752f));
        ((__hip_bfloat16*)outp)[(size_t)row * ldc + col] = __float2bfloat16(v);
      } else {
        v += bias[col] + res[(size_t)row * Nres + col];
        int gpix = row + row_base;
        int b = gpix >> 12, hw = gpix & 4095;
        ((float*)outp)[(size_t)(b * 256 + col) * HWSZ + hw] = v;
      }
    }
  }
}

// ---------------- dilated local attention: one thread per (pixel, head) ----------------
// Q: [16384][256]; KV: [16384][512] (K cols 0-255, V cols 256-511); out [16384][256]
__global__ __launch_bounds__(256) void attn2_k(
    const __hip_bfloat16* __restrict__ Q,
    const __hip_bfloat16* __restrict__ KV,
    __hip_bfloat16* __restrict__ out)
{
  int gid = blockIdx.x * 256 + threadIdx.x;
  int pix = gid >> 3, head = gid & 7;
  int dil = (head >> 1) + 1;
  int y = (pix >> 6) & 63, xc = pix & 63;
  int base = pix & ~4095;
  const short* q8 = (const short*)Q + (size_t)pix * 256 + head * 32;
  float qf[32];
  #pragma unroll
  for (int j = 0; j < 4; ++j) {
    bf16x8 v = *(const bf16x8*)(q8 + j * 8);
    #pragma unroll
    for (int e = 0; e < 8; ++e) qf[j*8 + e] = b2f(v[e]);
  }
  float lg[9];
  int npx[9];
  #pragma unroll
  for (int t = 0; t < 9; ++t) {
    int ny = y + (t / 3 - 1) * dil;
    int nx = xc + (t % 3 - 1) * dil;
    bool ok = ((unsigned)ny < 64u) && ((unsigned)nx < 64u);
    npx[t] = ok ? (base | (ny * 64 + nx)) : -1;
    float d = 0.f;
    if (ok) {
      const short* k8 = (const short*)KV + (size_t)npx[t] * 512 + head * 32;
      #pragma unroll
      for (int j = 0; j < 4; ++j) {
        bf16x8 v = *(const bf16x8*)(k8 + j * 8);
        #pragma unroll
        for (int e = 0; e < 8; ++e) d += qf[j*8 + e] * b2f(v[e]);
      }
    }
    lg[t] = d * 0.17677669529663687f;   // 32^-0.5
  }
  float m = lg[0];
  #pragma unroll
  for (int t = 1; t < 9; ++t) m = fmaxf(m, lg[t]);
  float w[9], den = 0.f;
  #pragma unroll
  for (int t = 0; t < 9; ++t) { w[t] = expf(lg[t] - m); den += w[t]; }
  float inv = 1.f / den;
  float acc[32];
  #pragma unroll
  for (int j = 0; j < 32; ++j) acc[j] = 0.f;
  #pragma unroll
  for (int t = 0; t < 9; ++t) {
    if (npx[t] >= 0) {
      const short* v8 = (const short*)KV + (size_t)npx[t] * 512 + 256 + head * 32;
      float wt = w[t];
      #pragma unroll
      for (int j = 0; j < 4; ++j) {
        bf16x8 v = *(const bf16x8*)(v8 + j * 8);
        #pragma unroll
        for (int e = 0; e < 8; ++e) acc[j*8 + e] += wt * b2f(v[e]);
      }
    }
  }
  short* op = (short*)out + (size_t)pix * 256 + head * 32;
  #pragma unroll
  for (int j = 0; j < 4; ++j) {
    bf16x8 o;
    #pragma unroll
    for (int e = 0; e < 8; ++e) o[e] = f2b(acc[j*8 + e] * inv);
    *(bf16x8*)(op + j * 8) = o;
  }
}

// ---------------- LN2: fp32 (pix,ch) -> bf16 (pix,ch) ----------------
__global__ __launch_bounds__(256) void ln2_k(
    const float* __restrict__ xm, const float* __restrict__ w2,
    const float* __restrict__ b2, __hip_bfloat16* __restrict__ h)
{
  int pix = blockIdx.x * 4 + (threadIdx.x >> 6);
  int l = threadIdx.x & 63;
  const float4 v = *(const float4*)(xm + (size_t)pix * 256 + l * 4);
  float s  = v.x + v.y + v.z + v.w;
  float ss = v.x*v.x + v.y*v.y + v.z*v.z + v.w*v.w;
  #pragma unroll
  for (int off = 32; off; off >>= 1) { s += __shfl_xor(s, off); ss += __shfl_xor(ss, off); }
  float mu = s * (1.f/256.f);
  float rstd = rsqrtf(ss * (1.f/256.f) - mu*mu + 1e-5f);
  float vv[4] = {v.x, v.y, v.z, v.w};
  #pragma unroll
  for (int j = 0; j < 4; ++j) {
    int c = l * 4 + j;
    h[(size_t)pix * 256 + c] = __float2bfloat16((vv[j] - mu) * rstd * w2[c] + b2[c]);
  }
}

extern "C" void kernel_launch(void* const* d_in, const int* in_sizes, int n_in,
                              void* d_out, int out_size, void* d_ws, size_t ws_size,
                              hipStream_t stream)
{
  const float* x   = (const float*)d_in[0];
  const float* n1w = (const float*)d_in[1];
  const float* n1b = (const float*)d_in[2];
  const float* qw  = (const float*)d_in[3];
  const float* kw  = (const float*)d_in[4];
  const float* vw  = (const float*)d_in[5];
  const float* pw  = (const float*)d_in[6];
  const float* pb  = (const float*)d_in[7];
  const float* n2w = (const float*)d_in[8];
  const float* n2b = (const float*)d_in[9];
  const float* f1w = (const float*)d_in[10];
  const float* f1b = (const float*)d_in[11];
  const float* f2w = (const float*)d_in[12];
  const float* f2b = (const float*)d_in[13];
  float* outp = (float*)d_out;
  char* ws = (char*)d_ws;

  const size_t MB = 1024 * 1024;
  // Workspace high-water 51 MB. Lifetimes per bi:
  //   [0,3)   wbf (whole session)
  //   [3,11)  ln1b -> attnb
  //   [11,27) diff fp32 -> h1h
  //   [27,35) qbuf --\
  //   [27,43)         xmid fp32 (after attn; overlaps dead qbuf + kv-low)
  //   [35,43) ln1a (overwritten by kv after Q gemm)
  //   [35,51) kv [16384][512] bf16
  //   [43,51) hb (after attn; kv dead)
  __hip_bfloat16* wbf   = (__hip_bfloat16*)(ws);
  __hip_bfloat16* ln1b  = (__hip_bfloat16*)(ws + 3*MB);
  __hip_bfloat16* attnb = (__hip_bfloat16*)(ws + 3*MB);
  float*          diff  = (float*)(ws + 11*MB);
  __hip_bfloat16* h1h   = (__hip_bfloat16*)(ws + 11*MB);
  __hip_bfloat16* qbuf  = (__hip_bfloat16*)(ws + 27*MB);
  float*          xmid  = (float*)(ws + 27*MB);
  __hip_bfloat16* ln1a  = (__hip_bfloat16*)(ws + 35*MB);
  __hip_bfloat16* kv    = (__hip_bfloat16*)(ws + 35*MB);
  __hip_bfloat16* hb    = (__hip_bfloat16*)(ws + 43*MB);

  convert_k<<<6144, 256, 0, stream>>>(qw, kw, vw, pw, f1w, f2w, wbf);

  for (int bi = 0; bi < 2; ++bi) {
    const short* wq = (const short*)(wbf + (size_t)bi * 786432);
    const short* wkv = wq + 65536;           // kw rows 0-255 then vw rows 256-511
    const short* wp  = wq + 196608;
    const short* w1  = wq + 262144;
    const short* w2  = wq + 524288;
    float av = (bi == 0) ? 1.f : -1.f, ai = (bi == 0) ? -1.f : 1.f;
    float bv = (bi == 0) ? 0.f : 1.f,  bb = (bi == 0) ? 1.f : 0.f;

    prep2_k<<<1024, 256, 0, stream>>>(x, n1w + bi*256, n1b + bi*256, ln1a, ln1b, diff, av, ai, bv, bb);

    gemm2_k<0,64><<<dim3(128,4), 256, 0, stream>>>((const short*)ln1a, wq,  qbuf, nullptr, nullptr, 256, 256, 0, 0);
    gemm2_k<0,64><<<dim3(128,8), 256, 0, stream>>>((const short*)ln1b, wkv, kv,   nullptr, nullptr, 256, 512, 0, 0);

    attn2_k<<<512, 256, 0, stream>>>(qbuf, kv, attnb);

    gemm2_k<1,64><<<dim3(128,4), 256, 0, stream>>>((const short*)attnb, wp, xmid, pb + bi*256, diff, 256, 256, 256, 0);
    ln2_k<<<4096, 256, 0, stream>>>(xmid, n2w + bi*256, n2b + bi*256, hb);

    float* outb = outp + (size_t)bi * 4194304;
    for (int pass = 0; pass < 2; ++pass) {
      const short* hbp = (const short*)hb + (size_t)pass * 8192 * 256;
      const float* xmp = xmid + (size_t)pass * 8192 * 256;
      gemm2_k<2,128><<<dim3(64,8), 256, 0, stream>>>(hbp, w1, h1h, f1b + bi*1024, nullptr, 256, 1024, 0, 0);
      gemm2_k<3,64><<<dim3(64,4), 256, 0, stream>>>((const short*)h1h, w2, outb, f2b + bi*256, xmp, 1024, 256, 256, pass * 8192);
    }
  }
}